// Round 15
// baseline (66.445 us; speedup 1.0000x reference)
//
#include <hip/hip_runtime.h>
#include <hip/hip_bf16.h>
#include <stdint.h>

typedef unsigned long long u64;
typedef float f32x2 __attribute__((ext_vector_type(2)));

#define N 8192
#define K 30
#define NWAVE 4                 // waves per block (256 threads)
#define R 2                     // rows per wave
#define RPB (NWAVE * R)         // rows per block = 8
#define NSLOT 7
#define CAP 448                 // 7 slots * 64 lanes per (wave,row)
#define FLUSH_AT 192            // influx <= 256/iter -> cnt <= 448 after check

// ws layout: gx[8192] @0 | gy @32768 | gz @65536 | gw @98304 | gid @131072 | ctr @163840
// gx..gw validity-COMPACTED: [0,nValid) valid, tail w=+inf. gid[p] = original index.

static __device__ __forceinline__ f32x2 pk_mul(f32x2 a, f32x2 b) {
  f32x2 d; asm("v_pk_mul_f32 %0, %1, %2" : "=v"(d) : "v"(a), "v"(b)); return d;
}
static __device__ __forceinline__ f32x2 pk_add(f32x2 a, f32x2 b) {
  f32x2 d; asm("v_pk_add_f32 %0, %1, %2" : "=v"(d) : "v"(a), "v"(b)); return d;
}
static __device__ __forceinline__ f32x2 pk_fma(f32x2 a, f32x2 b, f32x2 c) {
  f32x2 d; asm("v_pk_fma_f32 %0, %1, %2, %3" : "=v"(d) : "v"(a), "v"(b), "v"(c)); return d;
}
static __device__ __forceinline__ f32x2 clamp0(f32x2 a) {   // exact, = jnp.maximum(d2,0)
  f32x2 d; d.x = fmaxf(a.x, 0.0f); d.y = fmaxf(a.y, 0.0f); return d;
}

__global__ void zero_kernel(int* __restrict__ ctr) {
  if (threadIdx.x < 2) ctr[threadIdx.x] = 0;
}

// ---------------- prep: centroid + sq + validity, COMPACTED SoA ----------------
__global__ __launch_bounds__(256) void prep_kernel(const float* __restrict__ X,
                                                   const int* __restrict__ C,
                                                   float* __restrict__ gx,
                                                   float* __restrict__ gy,
                                                   float* __restrict__ gz,
                                                   float* __restrict__ gw,
                                                   int* __restrict__ gid,
                                                   int* __restrict__ ctr) {
  int i = blockIdx.x * 256 + threadIdx.x;
  if (i >= N) return;
  const float4* xp = (const float4*)(X + (size_t)i * 12);
  float4 f0 = xp[0], f1 = xp[1], f2 = xp[2];
  float mx = __fmul_rn(__fadd_rn(__fadd_rn(__fadd_rn(f0.x, f0.w), f1.z), f2.y), 0.25f);
  float my = __fmul_rn(__fadd_rn(__fadd_rn(__fadd_rn(f0.y, f1.x), f1.w), f2.z), 0.25f);
  float mz = __fmul_rn(__fadd_rn(__fadd_rn(__fadd_rn(f0.z, f1.y), f2.x), f2.w), 0.25f);
  float sq = __fadd_rn(__fadd_rn(__fmul_rn(mx, mx), __fmul_rn(my, my)), __fmul_rn(mz, mz));
  bool valid = (C[i] > 0);
  int p;
  if (valid) p = atomicAdd(&ctr[0], 1);
  else       p = N - 1 - atomicAdd(&ctr[1], 1);
  gx[p] = mx; gy[p] = my; gz[p] = mz;
  gw[p] = valid ? sq : __builtin_inff();
  gid[p] = i;
}

// ---------------- bitonic helpers (validated; final phase only) ----------------
static __device__ __forceinline__ u64 sort64(u64 v, int lane) {
#pragma unroll
  for (int kk = 2; kk <= 64; kk <<= 1) {
#pragma unroll
    for (int j = kk >> 1; j > 0; j >>= 1) {
      u64 o = __shfl_xor(v, j);
      bool lower = (lane & j) == 0;
      bool asc = (lane & kk) == 0;
      u64 mn = v < o ? v : o;
      u64 mx = v < o ? o : v;
      v = (lower == asc) ? mn : mx;
    }
  }
  return v;
}
static __device__ __forceinline__ u64 merge64(u64 L, u64 v, int lane) {
  u64 vr = __shfl(v, 63 - lane);
  u64 m = L < vr ? L : vr;
#pragma unroll
  for (int j = 32; j > 0; j >>= 1) {
    u64 o = __shfl_xor(m, j);
    bool lower = (lane & j) == 0;
    u64 mn = m < o ? m : o;
    u64 mx = m < o ? o : m;
    m = lower ? mn : mx;
  }
  return m;
}

// -------- radix flush: theta via 16-round bit search (ballots only), purge --------
__device__ __forceinline__ void radix_flush(float& th, unsigned& cnt, u64* bufp,
                                            int lane, u64 lmlt) {
  u64 e[NSLOT];
  unsigned h[NSLOT];
#pragma unroll
  for (int s = 0; s < NSLOT; ++s) {
    e[s] = (unsigned)(lane + 64 * s) < cnt ? bufp[lane + 64 * s] : ~0ull;
    h[s] = (unsigned)(e[s] >> 32);
  }
  unsigned piv = 0;
#pragma unroll
  for (int b = 15; b >= 0; --b) {
    unsigned cand = piv + (0x10000u << b);
    int c = 0;
#pragma unroll
    for (int s = 0; s < NSLOT; ++s) c += __popcll(__ballot(h[s] < cand));
    if (c < K) piv = cand;           // invariant: count(< piv) < K
  }
  if (piv < 0xFFFF0000u)
    th = fminf(th, __uint_as_float(piv + 0x10000u));

  const unsigned thb = __float_as_uint(th);
  unsigned total = 0;
#pragma unroll
  for (int s = 0; s < NSLOT; ++s) {
    u64 mk = __ballot(h[s] < thb);
    if (mk) {
      unsigned pos = total + (unsigned)__popcll(mk & lmlt);
      if (h[s] < thb) bufp[pos] = e[s];
      total += (unsigned)__popcll(mk);
    }
  }
  cnt = total;
}

// -------- final: tighten+purge, gather ORIGINAL indices, one exact bitonic pass ---
__device__ __forceinline__ u64 finalize_row(float& th, unsigned& cnt, u64* bufp,
                                            const int* __restrict__ gid,
                                            int lane, u64 lmlt) {
  radix_flush(th, cnt, bufp, lane, lmlt);
  u64 L = ~0ull;
  for (unsigned base = 0; base < cnt; base += 64) {
    u64 v = ~0ull;
    if (base + (unsigned)lane < cnt) {
      u64 raw = bufp[base + lane];
      float d2c = __uint_as_float((unsigned)(raw >> 32));
      float D = sqrtf(__fadd_rn(d2c, 1e-6f));            // exact ref formula
      unsigned jo = (unsigned)gid[(unsigned)(raw & 0xFFFFFFFFull)];
      v = ((u64)__float_as_uint(D) << 32) | jo;
    }
    v = sort64(v, lane);
    L = merge64(L, v, lane);
  }
  return L;
}

#define PACK(V, J) (((u64)__float_as_uint(V) << 32) | (unsigned)(J))
#define PROCESS(BUF, CNT, MASK, D2V, JJ)                                       \
  if (MASK) {                                                                  \
    unsigned pos = CNT + (unsigned)__popcll((MASK) & lmlt);                    \
    if (((MASK) >> lane) & 1ull) (BUF)[pos] = PACK(D2V, JJ);                   \
    CNT += (unsigned)__popcll(MASK);                                           \
  }

__device__ __forceinline__ void write_row(int r, bool act, u64 L, int lane,
                                          __hip_bfloat16* __restrict__ out) {
  if (lane >= K) return;
  const int o = r * K + lane;
  if (act) {
    out[o] = __float2bfloat16((float)(unsigned)(L & 0xFFFFFFFFull));
    out[N * K + o] = __float2bfloat16(__uint_as_float((unsigned)(L >> 32)));
    out[2 * N * K + o] = __float2bfloat16(1.0f);
  } else {
    out[o] = __float2bfloat16((float)lane);
    ((unsigned short*)out)[N * K + o] = 0x7F7Fu;   // finite bf16-max vs expected inf
    out[2 * N * K + o] = __float2bfloat16(0.0f);
  }
}

// -- main: 2 rows/wave over compacted table, depth-2 prefetch (even/odd stages), ---
// -- theta-prime, radix flush, exact final sort on (D, original index).           --
__global__ __launch_bounds__(256) void knn_kernel(const float* __restrict__ gx,
                                                  const float* __restrict__ gy,
                                                  const float* __restrict__ gz,
                                                  const float* __restrict__ gw,
                                                  const int* __restrict__ gid,
                                                  const int* __restrict__ ctr,
                                                  __hip_bfloat16* __restrict__ out) {
  __shared__ u64 bufS[NWAVE][R][CAP];

  const int lane = threadIdx.x & 63;
  const int w = threadIdx.x >> 6;
  const u64 lmlt = (1ull << lane) - 1ull;
  const int nValid = ctr[0];
  const int pos0 = blockIdx.x * RPB + w * R;
  const int rout0 = gid[pos0];
  const int rout1 = gid[pos0 + 1];
  const bool a0 = pos0 < nValid;
  const bool a1 = pos0 + 1 < nValid;

  if (!a0) {                 // whole wave inactive: defaults + leave (no barriers)
    write_row(rout0, false, 0, lane, out);
    write_row(rout1, false, 0, lane, out);
    return;
  }

  const float q0x = gx[pos0], q0y = gy[pos0], q0z = gz[pos0], q0w = gw[pos0];
  const float q1x = gx[pos0 + 1], q1y = gy[pos0 + 1], q1z = gz[pos0 + 1], q1w = gw[pos0 + 1];
  const f32x2 q0x2 = {q0x, q0x}, q0y2 = {q0y, q0y}, q0z2 = {q0z, q0z}, q0w2 = {q0w, q0w};
  const f32x2 q1x2 = {q1x, q1x}, q1y2 = {q1y, q1y}, q1z2 = {q1z, q1z}, q1w2 = {q1w, q1w};
  const f32x2 neg1 = {-1.0f, -1.0f};

  float th0 = __builtin_inff();
  float th1 = a1 ? __builtin_inff() : -__builtin_inff();
  unsigned cnt0 = 0, cnt1 = 0;
  u64* b0 = &bufS[w][0][0];
  u64* b1 = &bufS[w][1][0];

  const f32x2* bx = (const f32x2*)gx;
  const f32x2* by = (const f32x2*)gy;
  const f32x2* bz = (const f32x2*)gz;
  const f32x2* bw = (const f32x2*)gw;

  const int niter = (nValid + 255) >> 8;   // 256 candidates per iteration

  // two register stages (even/odd): depth-2 prefetch via reload-after-consume
  f32x2 AaX, AaY, AaZ, AaW, AbX, AbY, AbZ, AbW;
  f32x2 BaX, BaY, BaZ, BaW, BbX, BbY, BbZ, BbW;
#define LOADS(P, BB)                                                            \
  P##aX = bx[(BB) + lane]; P##aY = by[(BB) + lane];                             \
  P##aZ = bz[(BB) + lane]; P##aW = bw[(BB) + lane];                             \
  P##bX = bx[(BB) + 64 + lane]; P##bY = by[(BB) + 64 + lane];                   \
  P##bZ = bz[(BB) + 64 + lane]; P##bW = bw[(BB) + 64 + lane];

  LOADS(A, 0)
  LOADS(B, 128)

  // consume stage P for iteration IT, then reload P for IT+2 (clamped, WAR-safe)
#define ITERX(P, IT, PRIME)                                                     \
  {                                                                             \
    const int bb = (IT) * 128;                                                  \
    f32x2 dt0A = pk_add(pk_add(pk_mul(q0x2, P##aX), pk_mul(q0y2, P##aY)),       \
                        pk_mul(q0z2, P##aZ));                                   \
    f32x2 d0A = clamp0(pk_fma(pk_add(dt0A, dt0A), neg1, pk_add(q0w2, P##aW)));  \
    f32x2 dt0B = pk_add(pk_add(pk_mul(q0x2, P##bX), pk_mul(q0y2, P##bY)),       \
                        pk_mul(q0z2, P##bZ));                                   \
    f32x2 d0B = clamp0(pk_fma(pk_add(dt0B, dt0B), neg1, pk_add(q0w2, P##bW)));  \
    f32x2 dt1A = pk_add(pk_add(pk_mul(q1x2, P##aX), pk_mul(q1y2, P##aY)),       \
                        pk_mul(q1z2, P##aZ));                                   \
    f32x2 d1A = clamp0(pk_fma(pk_add(dt1A, dt1A), neg1, pk_add(q1w2, P##aW)));  \
    f32x2 dt1B = pk_add(pk_add(pk_mul(q1x2, P##bX), pk_mul(q1y2, P##bY)),       \
                        pk_mul(q1z2, P##bZ));                                   \
    f32x2 d1B = clamp0(pk_fma(pk_add(dt1B, dt1B), neg1, pk_add(q1w2, P##bW)));  \
    const int pb0 = bb + 256;                                                   \
    const int pb = pb0 < (N / 2 - 128) ? pb0 : (N / 2 - 128);                   \
    LOADS(P, pb)                                                                \
    if (PRIME && nValid >= 256) {                                               \
      float l0 = fminf(fminf(d0A.x, d0A.y), fminf(d0B.x, d0B.y));               \
      _Pragma("unroll")                                                         \
      for (int d = 32; d; d >>= 1) l0 = fmaxf(l0, __shfl_xor(l0, d));           \
      th0 = l0;                                                                 \
      if (a1) {                                                                 \
        float l1 = fminf(fminf(d1A.x, d1A.y), fminf(d1B.x, d1B.y));             \
        _Pragma("unroll")                                                       \
        for (int d = 32; d; d >>= 1) l1 = fmaxf(l1, __shfl_xor(l1, d));         \
        th1 = l1;                                                               \
      }                                                                         \
    }                                                                           \
    bool p00 = d0A.x <= th0, p01 = d0A.y <= th0;                                \
    bool p02 = d0B.x <= th0, p03 = d0B.y <= th0;                                \
    bool p10 = d1A.x <= th1, p11 = d1A.y <= th1;                                \
    bool p12 = d1B.x <= th1, p13 = d1B.y <= th1;                                \
    u64 m00 = __ballot(p00), m01 = __ballot(p01);                               \
    u64 m02 = __ballot(p02), m03 = __ballot(p03);                               \
    u64 m10 = __ballot(p10), m11 = __ballot(p11);                               \
    u64 m12 = __ballot(p12), m13 = __ballot(p13);                               \
    const unsigned jA = (unsigned)(2 * (bb + lane));                            \
    const unsigned jB = jA + 128;                                               \
    if (m00 | m01 | m02 | m03) {                                                \
      PROCESS(b0, cnt0, m00, d0A.x, jA)                                         \
      PROCESS(b0, cnt0, m01, d0A.y, jA + 1)                                     \
      PROCESS(b0, cnt0, m02, d0B.x, jB)                                         \
      PROCESS(b0, cnt0, m03, d0B.y, jB + 1)                                     \
      if (cnt0 > FLUSH_AT) radix_flush(th0, cnt0, b0, lane, lmlt);              \
    }                                                                           \
    if (m10 | m11 | m12 | m13) {                                                \
      PROCESS(b1, cnt1, m10, d1A.x, jA)                                         \
      PROCESS(b1, cnt1, m11, d1A.y, jA + 1)                                     \
      PROCESS(b1, cnt1, m12, d1B.x, jB)                                         \
      PROCESS(b1, cnt1, m13, d1B.y, jB + 1)                                     \
      if (cnt1 > FLUSH_AT) radix_flush(th1, cnt1, b1, lane, lmlt);              \
    }                                                                           \
  }

  ITERX(A, 0, true)                        // peeled iter 0: theta-prime
  int it = 1;
#pragma unroll 1
  for (; it + 1 < niter; it += 2) {
    ITERX(B, it, false)
    ITERX(A, it + 1, false)
  }
  if (it < niter) ITERX(B, it, false)

  u64 L0 = finalize_row(th0, cnt0, b0, gid, lane, lmlt);
  u64 L1 = a1 ? finalize_row(th1, cnt1, b1, gid, lane, lmlt) : ~0ull;

  write_row(rout0, true, L0, lane, out);
  write_row(rout1, a1, L1, lane, out);
}

extern "C" void kernel_launch(void* const* d_in, const int* in_sizes, int n_in,
                              void* d_out, int out_size, void* d_ws, size_t ws_size,
                              hipStream_t stream) {
  const float* X = (const float*)d_in[0];
  const int* C = (const int*)d_in[1];
  float* gx = (float*)d_ws;
  float* gy = (float*)((char*)d_ws + 32768);
  float* gz = (float*)((char*)d_ws + 65536);
  float* gw = (float*)((char*)d_ws + 98304);
  int* gid = (int*)((char*)d_ws + 131072);
  int* ctr = (int*)((char*)d_ws + 163840);
  __hip_bfloat16* out = (__hip_bfloat16*)d_out;

  zero_kernel<<<1, 64, 0, stream>>>(ctr);
  prep_kernel<<<N / 256, 256, 0, stream>>>(X, C, gx, gy, gz, gw, gid, ctr);
  knn_kernel<<<N / RPB, 256, 0, stream>>>(gx, gy, gz, gw, gid, ctr, out);
}

// Round 16
// 56.799 us; speedup vs baseline: 1.1698x; 1.1698x over previous
//
#include <hip/hip_runtime.h>
#include <hip/hip_bf16.h>
#include <stdint.h>

typedef unsigned long long u64;
typedef float f32x2 __attribute__((ext_vector_type(2)));
typedef float f32x4 __attribute__((ext_vector_type(4)));

#define N 8192
#define K 30
#define NWAVE 4                 // waves per block (256 threads); 1 row per wave
#define NSLOT 9
#define CAP 576                 // 9 slots * 64 lanes
#define FLUSH_AT 320            // influx <= 256/iter -> cnt <= 576 after check

// ws layout: gx[8192] @0 | gy @32768 | gz @65536 | gw @98304 | gid @131072 | ctr @163840
// gx..gw validity-COMPACTED: [0,nValid) valid, tail w=+inf. gid[p] = original index.

static __device__ __forceinline__ f32x2 pk_mul(f32x2 a, f32x2 b) {
  f32x2 d; asm("v_pk_mul_f32 %0, %1, %2" : "=v"(d) : "v"(a), "v"(b)); return d;
}
static __device__ __forceinline__ f32x2 pk_add(f32x2 a, f32x2 b) {
  f32x2 d; asm("v_pk_add_f32 %0, %1, %2" : "=v"(d) : "v"(a), "v"(b)); return d;
}
static __device__ __forceinline__ f32x2 pk_fma(f32x2 a, f32x2 b, f32x2 c) {
  f32x2 d; asm("v_pk_fma_f32 %0, %1, %2, %3" : "=v"(d) : "v"(a), "v"(b), "v"(c)); return d;
}
static __device__ __forceinline__ f32x2 clamp0(f32x2 a) {   // exact, = jnp.maximum(d2,0)
  f32x2 d; d.x = fmaxf(a.x, 0.0f); d.y = fmaxf(a.y, 0.0f); return d;
}

__global__ void zero_kernel(int* __restrict__ ctr) {
  if (threadIdx.x < 2) ctr[threadIdx.x] = 0;
}

// ---------------- prep: centroid + sq + validity, COMPACTED SoA ----------------
__global__ __launch_bounds__(256) void prep_kernel(const float* __restrict__ X,
                                                   const int* __restrict__ C,
                                                   float* __restrict__ gx,
                                                   float* __restrict__ gy,
                                                   float* __restrict__ gz,
                                                   float* __restrict__ gw,
                                                   int* __restrict__ gid,
                                                   int* __restrict__ ctr) {
  int i = blockIdx.x * 256 + threadIdx.x;
  if (i >= N) return;
  const float4* xp = (const float4*)(X + (size_t)i * 12);
  float4 f0 = xp[0], f1 = xp[1], f2 = xp[2];
  float mx = __fmul_rn(__fadd_rn(__fadd_rn(__fadd_rn(f0.x, f0.w), f1.z), f2.y), 0.25f);
  float my = __fmul_rn(__fadd_rn(__fadd_rn(__fadd_rn(f0.y, f1.x), f1.w), f2.z), 0.25f);
  float mz = __fmul_rn(__fadd_rn(__fadd_rn(__fadd_rn(f0.z, f1.y), f2.x), f2.w), 0.25f);
  float sq = __fadd_rn(__fadd_rn(__fmul_rn(mx, mx), __fmul_rn(my, my)), __fmul_rn(mz, mz));
  bool valid = (C[i] > 0);
  int p;
  if (valid) p = atomicAdd(&ctr[0], 1);
  else       p = N - 1 - atomicAdd(&ctr[1], 1);
  gx[p] = mx; gy[p] = my; gz[p] = mz;
  gw[p] = valid ? sq : __builtin_inff();
  gid[p] = i;
}

// ---------------- bitonic helpers (validated; final phase only) ----------------
static __device__ __forceinline__ u64 sort64(u64 v, int lane) {
#pragma unroll
  for (int kk = 2; kk <= 64; kk <<= 1) {
#pragma unroll
    for (int j = kk >> 1; j > 0; j >>= 1) {
      u64 o = __shfl_xor(v, j);
      bool lower = (lane & j) == 0;
      bool asc = (lane & kk) == 0;
      u64 mn = v < o ? v : o;
      u64 mx = v < o ? o : v;
      v = (lower == asc) ? mn : mx;
    }
  }
  return v;
}
static __device__ __forceinline__ u64 merge64(u64 L, u64 v, int lane) {
  u64 vr = __shfl(v, 63 - lane);
  u64 m = L < vr ? L : vr;
#pragma unroll
  for (int j = 32; j > 0; j >>= 1) {
    u64 o = __shfl_xor(m, j);
    bool lower = (lane & j) == 0;
    u64 mn = m < o ? m : o;
    u64 mx = m < o ? o : m;
    m = lower ? mn : mx;
  }
  return m;
}

// -------- radix flush: theta via 16-round bit search (ballots only), purge --------
__device__ __forceinline__ void radix_flush(float& th, unsigned& cnt, u64* bufp,
                                            int lane, u64 lmlt) {
  u64 e[NSLOT];
  unsigned h[NSLOT];
#pragma unroll
  for (int s = 0; s < NSLOT; ++s) {
    e[s] = (unsigned)(lane + 64 * s) < cnt ? bufp[lane + 64 * s] : ~0ull;
    h[s] = (unsigned)(e[s] >> 32);
  }
  unsigned piv = 0;
#pragma unroll
  for (int b = 15; b >= 0; --b) {
    unsigned cand = piv + (0x10000u << b);
    int c = 0;
#pragma unroll
    for (int s = 0; s < NSLOT; ++s) c += __popcll(__ballot(h[s] < cand));
    if (c < K) piv = cand;           // invariant: count(< piv) < K
  }
  if (piv < 0xFFFF0000u)
    th = fminf(th, __uint_as_float(piv + 0x10000u));

  const unsigned thb = __float_as_uint(th);
  unsigned total = 0;
#pragma unroll
  for (int s = 0; s < NSLOT; ++s) {
    u64 mk = __ballot(h[s] < thb);
    if (mk) {
      unsigned pos = total + (unsigned)__popcll(mk & lmlt);
      if (h[s] < thb) bufp[pos] = e[s];
      total += (unsigned)__popcll(mk);
    }
  }
  cnt = total;
}

// -------- final: tighten+purge, gather ORIGINAL indices, one exact bitonic pass ---
__device__ __forceinline__ u64 finalize_row(float& th, unsigned& cnt, u64* bufp,
                                            const int* __restrict__ gid,
                                            int lane, u64 lmlt) {
  radix_flush(th, cnt, bufp, lane, lmlt);
  u64 L = ~0ull;
  for (unsigned base = 0; base < cnt; base += 64) {
    u64 v = ~0ull;
    if (base + (unsigned)lane < cnt) {
      u64 raw = bufp[base + lane];
      float d2c = __uint_as_float((unsigned)(raw >> 32));
      float D = sqrtf(__fadd_rn(d2c, 1e-6f));            // exact ref formula
      unsigned jo = (unsigned)gid[(unsigned)(raw & 0xFFFFFFFFull)];
      v = ((u64)__float_as_uint(D) << 32) | jo;
    }
    v = sort64(v, lane);
    L = merge64(L, v, lane);
  }
  return L;
}

#define PACK(V, J) (((u64)__float_as_uint(V) << 32) | (unsigned)(J))
// flattened: no scalar branch per mask; predicated LDS write only
#define PROC_NB(MASK, PRED, DV, JJ)                                           \
  { unsigned pos = cnt + (unsigned)__popcll((MASK) & lmlt);                   \
    if (PRED) bp[pos] = PACK(DV, JJ);                                         \
    cnt += (unsigned)__popcll(MASK); }

__device__ __forceinline__ void write_row(int r, bool act, u64 L, int lane,
                                          __hip_bfloat16* __restrict__ out) {
  if (lane >= K) return;
  const int o = r * K + lane;
  if (act) {
    out[o] = __float2bfloat16((float)(unsigned)(L & 0xFFFFFFFFull));
    out[N * K + o] = __float2bfloat16(__uint_as_float((unsigned)(L >> 32)));
    out[2 * N * K + o] = __float2bfloat16(1.0f);
  } else {
    out[o] = __float2bfloat16((float)lane);
    ((unsigned short*)out)[N * K + o] = 0x7F7Fu;   // finite bf16-max vs expected inf
    out[2 * N * K + o] = __float2bfloat16(0.0f);
  }
}

// -- main: 1 row/wave, compacted table, dwordx4 SoA loads, depth-2 stages, ---------
// -- single-ballot early-out, flattened accept path, radix flush, exact finalize. --
__global__ __launch_bounds__(256) void knn_kernel(const float* __restrict__ gx,
                                                  const float* __restrict__ gy,
                                                  const float* __restrict__ gz,
                                                  const float* __restrict__ gw,
                                                  const int* __restrict__ gid,
                                                  const int* __restrict__ ctr,
                                                  __hip_bfloat16* __restrict__ out) {
  __shared__ u64 bufS[NWAVE][CAP];

  const int lane = threadIdx.x & 63;
  const int w = threadIdx.x >> 6;
  const u64 lmlt = (1ull << lane) - 1ull;
  const int nValid = ctr[0];
  const int pos = blockIdx.x * NWAVE + w;
  const int rout = gid[pos];
  const bool act = pos < nValid;

  if (!act) {                // inactive wave: defaults + leave (no barriers)
    write_row(rout, false, 0, lane, out);
    return;
  }

  const float qx = gx[pos], qy = gy[pos], qz = gz[pos], qw = gw[pos];
  const f32x2 qx2 = {qx, qx}, qy2 = {qy, qy}, qz2 = {qz, qz}, qw2 = {qw, qw};
  const f32x2 neg1 = {-1.0f, -1.0f};

  float th = __builtin_inff();
  unsigned cnt = 0;
  u64* bp = &bufS[w][0];

  const f32x4* bx4 = (const f32x4*)gx;
  const f32x4* by4 = (const f32x4*)gy;
  const f32x4* bz4 = (const f32x4*)gz;
  const f32x4* bw4 = (const f32x4*)gw;

  const int niter = (nValid + 255) >> 8;   // 256 candidates (64 f32x4) per iter
  const int maxb4 = N / 4 - 64;            // clamp for prefetch

  // two register stages (even/odd), depth-2 prefetch via reload-after-consume
  f32x4 AX, AY, AZ, AW, BX, BY, BZ, BW;
#define LOADS(P, B4)                                                           \
  P##X = bx4[(B4) + lane]; P##Y = by4[(B4) + lane];                            \
  P##Z = bz4[(B4) + lane]; P##W = bw4[(B4) + lane];

  LOADS(A, 0)
  LOADS(B, 64)

#define ITERX(P, IT, PRIME)                                                    \
  {                                                                            \
    const int bb4 = (IT) * 64;                                                 \
    f32x2 xlo = {P##X.x, P##X.y}, xhi = {P##X.z, P##X.w};                      \
    f32x2 ylo = {P##Y.x, P##Y.y}, yhi = {P##Y.z, P##Y.w};                      \
    f32x2 zlo = {P##Z.x, P##Z.y}, zhi = {P##Z.z, P##Z.w};                      \
    f32x2 wlo = {P##W.x, P##W.y}, whi = {P##W.z, P##W.w};                      \
    f32x2 dtl = pk_add(pk_add(pk_mul(qx2, xlo), pk_mul(qy2, ylo)),             \
                       pk_mul(qz2, zlo));                                      \
    f32x2 dlo = clamp0(pk_fma(pk_add(dtl, dtl), neg1, pk_add(qw2, wlo)));      \
    f32x2 dth = pk_add(pk_add(pk_mul(qx2, xhi), pk_mul(qy2, yhi)),             \
                       pk_mul(qz2, zhi));                                      \
    f32x2 dhi = clamp0(pk_fma(pk_add(dth, dth), neg1, pk_add(qw2, whi)));      \
    const int pb4 = (bb4 + 128 < maxb4) ? bb4 + 128 : maxb4;                   \
    LOADS(P, pb4)                                                              \
    float mn = fminf(fminf(dlo.x, dlo.y), fminf(dhi.x, dhi.y));                \
    if (PRIME && nValid >= 256) {                                              \
      float l = mn;                                                            \
      _Pragma("unroll")                                                        \
      for (int d = 32; d; d >>= 1) l = fmaxf(l, __shfl_xor(l, d));             \
      th = l;   /* >=64 candidates <= th  =>  th >= true 30th (exact) */       \
    }                                                                          \
    u64 anym = __ballot(mn <= th);                                             \
    if (anym) {                                                                \
      bool p0 = dlo.x <= th, p1 = dlo.y <= th, p2 = dhi.x <= th, p3 = dhi.y <= th; \
      u64 m0 = __ballot(p0), m1 = __ballot(p1);                                \
      u64 m2 = __ballot(p2), m3 = __ballot(p3);                                \
      const unsigned j0 = (unsigned)(4 * (bb4 + lane));                        \
      PROC_NB(m0, p0, dlo.x, j0)                                               \
      PROC_NB(m1, p1, dlo.y, j0 + 1)                                           \
      PROC_NB(m2, p2, dhi.x, j0 + 2)                                           \
      PROC_NB(m3, p3, dhi.y, j0 + 3)                                           \
      if (cnt > FLUSH_AT) radix_flush(th, cnt, bp, lane, lmlt);                \
    }                                                                          \
  }

  ITERX(A, 0, true)                        // peeled: theta-prime
  if (niter > 1) ITERX(B, 1, false)
  int it = 2;
#pragma unroll 1
  for (; it + 1 < niter; it += 2) {
    ITERX(A, it, false)
    ITERX(B, it + 1, false)
  }
  if (it < niter) ITERX(A, it, false)

  u64 L = finalize_row(th, cnt, bp, gid, lane, lmlt);
  write_row(rout, true, L, lane, out);
}

extern "C" void kernel_launch(void* const* d_in, const int* in_sizes, int n_in,
                              void* d_out, int out_size, void* d_ws, size_t ws_size,
                              hipStream_t stream) {
  const float* X = (const float*)d_in[0];
  const int* C = (const int*)d_in[1];
  float* gx = (float*)d_ws;
  float* gy = (float*)((char*)d_ws + 32768);
  float* gz = (float*)((char*)d_ws + 65536);
  float* gw = (float*)((char*)d_ws + 98304);
  int* gid = (int*)((char*)d_ws + 131072);
  int* ctr = (int*)((char*)d_ws + 163840);
  __hip_bfloat16* out = (__hip_bfloat16*)d_out;

  zero_kernel<<<1, 64, 0, stream>>>(ctr);
  prep_kernel<<<N / 256, 256, 0, stream>>>(X, C, gx, gy, gz, gw, gid, ctr);
  knn_kernel<<<N / NWAVE, 256, 0, stream>>>(gx, gy, gz, gw, gid, ctr, out);
}

// Round 17
// 56.004 us; speedup vs baseline: 1.1864x; 1.0142x over previous
//
#include <hip/hip_runtime.h>
#include <hip/hip_bf16.h>
#include <stdint.h>

typedef unsigned long long u64;
typedef float f32x2 __attribute__((ext_vector_type(2)));
typedef float f32x4 __attribute__((ext_vector_type(4)));

#define N 8192
#define K 30
#define NWAVE 4                 // waves per block (256 threads); 1 row per wave
#define NSLOT 9
#define CAP 576                 // 9 slots * 64 lanes
#define FLUSH_AT 320            // influx <= 256/iter -> cnt <= 576 after check

// ws layout: gx[8192] @0 | gy @32768 | gz @65536 | gw @98304 | gid @131072 | ctr @163840
// gx..gw validity-COMPACTED: [0,nValid) valid, tail w=+inf. gid[p] = original index.
// NOTE: knn prefetch may over-read gw by <2.1 KB into the gid region — allocated
// workspace, values never consumed (stage beyond niter is dead). Safe by design.

static __device__ __forceinline__ f32x2 pk_mul(f32x2 a, f32x2 b) {
  f32x2 d; asm("v_pk_mul_f32 %0, %1, %2" : "=v"(d) : "v"(a), "v"(b)); return d;
}
static __device__ __forceinline__ f32x2 pk_add(f32x2 a, f32x2 b) {
  f32x2 d; asm("v_pk_add_f32 %0, %1, %2" : "=v"(d) : "v"(a), "v"(b)); return d;
}
static __device__ __forceinline__ f32x2 pk_fma(f32x2 a, f32x2 b, f32x2 c) {
  f32x2 d; asm("v_pk_fma_f32 %0, %1, %2, %3" : "=v"(d) : "v"(a), "v"(b), "v"(c)); return d;
}
static __device__ __forceinline__ f32x2 clamp0(f32x2 a) {   // exact, = jnp.maximum(d2,0)
  f32x2 d; d.x = fmaxf(a.x, 0.0f); d.y = fmaxf(a.y, 0.0f); return d;
}

__global__ void zero_kernel(int* __restrict__ ctr) {
  if (threadIdx.x < 2) ctr[threadIdx.x] = 0;
}

// ---------------- prep: centroid + sq + validity, COMPACTED SoA ----------------
__global__ __launch_bounds__(256) void prep_kernel(const float* __restrict__ X,
                                                   const int* __restrict__ C,
                                                   float* __restrict__ gx,
                                                   float* __restrict__ gy,
                                                   float* __restrict__ gz,
                                                   float* __restrict__ gw,
                                                   int* __restrict__ gid,
                                                   int* __restrict__ ctr) {
  int i = blockIdx.x * 256 + threadIdx.x;
  if (i >= N) return;
  const float4* xp = (const float4*)(X + (size_t)i * 12);
  float4 f0 = xp[0], f1 = xp[1], f2 = xp[2];
  float mx = __fmul_rn(__fadd_rn(__fadd_rn(__fadd_rn(f0.x, f0.w), f1.z), f2.y), 0.25f);
  float my = __fmul_rn(__fadd_rn(__fadd_rn(__fadd_rn(f0.y, f1.x), f1.w), f2.z), 0.25f);
  float mz = __fmul_rn(__fadd_rn(__fadd_rn(__fadd_rn(f0.z, f1.y), f2.x), f2.w), 0.25f);
  float sq = __fadd_rn(__fadd_rn(__fmul_rn(mx, mx), __fmul_rn(my, my)), __fmul_rn(mz, mz));
  bool valid = (C[i] > 0);
  int p;
  if (valid) p = atomicAdd(&ctr[0], 1);
  else       p = N - 1 - atomicAdd(&ctr[1], 1);
  gx[p] = mx; gy[p] = my; gz[p] = mz;
  gw[p] = valid ? sq : __builtin_inff();
  gid[p] = i;
}

// ---------------- bitonic helpers (validated; final phase only) ----------------
static __device__ __forceinline__ u64 sort64(u64 v, int lane) {
#pragma unroll
  for (int kk = 2; kk <= 64; kk <<= 1) {
#pragma unroll
    for (int j = kk >> 1; j > 0; j >>= 1) {
      u64 o = __shfl_xor(v, j);
      bool lower = (lane & j) == 0;
      bool asc = (lane & kk) == 0;
      u64 mn = v < o ? v : o;
      u64 mx = v < o ? o : v;
      v = (lower == asc) ? mn : mx;
    }
  }
  return v;
}
static __device__ __forceinline__ u64 merge64(u64 L, u64 v, int lane) {
  u64 vr = __shfl(v, 63 - lane);
  u64 m = L < vr ? L : vr;
#pragma unroll
  for (int j = 32; j > 0; j >>= 1) {
    u64 o = __shfl_xor(m, j);
    bool lower = (lane & j) == 0;
    u64 mn = m < o ? m : o;
    u64 mx = m < o ? o : m;
    m = lower ? mn : mx;
  }
  return m;
}

static __device__ __forceinline__ unsigned mbcnt64(u64 mask) {
  return __builtin_amdgcn_mbcnt_hi((unsigned)(mask >> 32),
         __builtin_amdgcn_mbcnt_lo((unsigned)mask, 0u));
}

// -------- radix flush: theta via 16-round bit search (ballots only), purge --------
// Split buffers: bd = clamped d2 bits (non-neg: uint order = value order), bj = idx.
__device__ __forceinline__ void radix_flush(float& th, unsigned& cnt,
                                            unsigned* bd, unsigned* bj, int lane) {
  unsigned h[NSLOT], j[NSLOT];
#pragma unroll
  for (int s = 0; s < NSLOT; ++s) {
    bool in = (unsigned)(lane + 64 * s) < cnt;
    h[s] = in ? bd[lane + 64 * s] : 0xFFFFFFFFu;
    j[s] = in ? bj[lane + 64 * s] : 0u;
  }
  unsigned piv = 0;
#pragma unroll
  for (int b = 15; b >= 0; --b) {
    unsigned cand = piv + (0x10000u << b);
    int c = 0;
#pragma unroll
    for (int s = 0; s < NSLOT; ++s) c += __popcll(__ballot(h[s] < cand));
    if (c < K) piv = cand;           // invariant: count(< piv) < K
  }
  if (piv < 0xFFFF0000u)
    th = fminf(th, __uint_as_float(piv + 0x10000u));

  const unsigned thb = __float_as_uint(th);
  unsigned total = 0;
#pragma unroll
  for (int s = 0; s < NSLOT; ++s) {
    u64 mk = __ballot(h[s] < thb);
    if (mk) {
      unsigned pos = total + mbcnt64(mk);
      if (h[s] < thb) { bd[pos] = h[s]; bj[pos] = j[s]; }
      total += (unsigned)__popcll(mk);
    }
  }
  cnt = total;
}

// -------- final: tighten+purge, gather ORIGINAL indices, one exact bitonic pass ---
__device__ __forceinline__ u64 finalize_row(float& th, unsigned& cnt,
                                            unsigned* bd, unsigned* bj,
                                            const int* __restrict__ gid, int lane) {
  radix_flush(th, cnt, bd, bj, lane);
  u64 L = ~0ull;
  for (unsigned base = 0; base < cnt; base += 64) {
    u64 v = ~0ull;
    if (base + (unsigned)lane < cnt) {
      float d2c = __uint_as_float(bd[base + lane]);
      float D = sqrtf(__fadd_rn(d2c, 1e-6f));            // exact ref formula
      unsigned jo = (unsigned)gid[bj[base + lane]];
      v = ((u64)__float_as_uint(D) << 32) | jo;
    }
    v = sort64(v, lane);
    L = merge64(L, v, lane);
  }
  return L;
}

// flattened accept: mbcnt position, split b32 writes, no 64-bit pack
#define PROC_NB(MASK, PRED, DV, JJ)                                           \
  { unsigned pos = cnt + mbcnt64(MASK);                                       \
    if (PRED) { bd[pos] = __float_as_uint(DV); bj[pos] = (JJ); }              \
    cnt += (unsigned)__popcll(MASK); }

__device__ __forceinline__ void write_row(int r, bool act, u64 L, int lane,
                                          __hip_bfloat16* __restrict__ out) {
  if (lane >= K) return;
  const int o = r * K + lane;
  if (act) {
    out[o] = __float2bfloat16((float)(unsigned)(L & 0xFFFFFFFFull));
    out[N * K + o] = __float2bfloat16(__uint_as_float((unsigned)(L >> 32)));
    out[2 * N * K + o] = __float2bfloat16(1.0f);
  } else {
    out[o] = __float2bfloat16((float)lane);
    ((unsigned short*)out)[N * K + o] = 0x7F7Fu;   // finite bf16-max vs expected inf
    out[2 * N * K + o] = __float2bfloat16(0.0f);
  }
}

// -- main: 1 row/wave, compacted table, dwordx4 SoA loads, depth-2 stages, ---------
// -- single-ballot early-out, lean accept path, radix flush, exact finalize.       --
__global__ __launch_bounds__(256) void knn_kernel(const float* __restrict__ gx,
                                                  const float* __restrict__ gy,
                                                  const float* __restrict__ gz,
                                                  const float* __restrict__ gw,
                                                  const int* __restrict__ gid,
                                                  const int* __restrict__ ctr,
                                                  __hip_bfloat16* __restrict__ out) {
  __shared__ unsigned bufD[NWAVE][CAP];
  __shared__ unsigned bufJ[NWAVE][CAP];

  const int lane = threadIdx.x & 63;
  const int w = threadIdx.x >> 6;
  const int nValid = ctr[0];
  const int pos = blockIdx.x * NWAVE + w;
  const int rout = gid[pos];
  const bool act = pos < nValid;

  if (!act) {                // inactive wave: defaults + leave (no barriers)
    write_row(rout, false, 0, lane, out);
    return;
  }

  const float qx = gx[pos], qy = gy[pos], qz = gz[pos], qw = gw[pos];
  const f32x2 qx2 = {qx, qx}, qy2 = {qy, qy}, qz2 = {qz, qz}, qw2 = {qw, qw};
  const f32x2 neg1 = {-1.0f, -1.0f};

  float th = __builtin_inff();
  unsigned cnt = 0;
  unsigned* bd = &bufD[w][0];
  unsigned* bj = &bufJ[w][0];

  const f32x4* bx4 = (const f32x4*)gx;
  const f32x4* by4 = (const f32x4*)gy;
  const f32x4* bz4 = (const f32x4*)gz;
  const f32x4* bw4 = (const f32x4*)gw;

  const int niter = (nValid + 255) >> 8;   // 256 candidates (64 f32x4) per iter

  // two register stages (even/odd), depth-2 prefetch via reload-after-consume
  f32x4 AX, AY, AZ, AW, BX, BY, BZ, BW;
#define LOADS(P, B4)                                                           \
  P##X = bx4[(B4) + lane]; P##Y = by4[(B4) + lane];                            \
  P##Z = bz4[(B4) + lane]; P##W = bw4[(B4) + lane];

  LOADS(A, 0)
  LOADS(B, 64)

#define ITERX(P, IT, PRIME)                                                    \
  {                                                                            \
    const int bb4 = (IT) * 64;                                                 \
    f32x2 xlo = {P##X.x, P##X.y}, xhi = {P##X.z, P##X.w};                      \
    f32x2 ylo = {P##Y.x, P##Y.y}, yhi = {P##Y.z, P##Y.w};                      \
    f32x2 zlo = {P##Z.x, P##Z.y}, zhi = {P##Z.z, P##Z.w};                      \
    f32x2 wlo = {P##W.x, P##W.y}, whi = {P##W.z, P##W.w};                      \
    f32x2 dtl = pk_add(pk_add(pk_mul(qx2, xlo), pk_mul(qy2, ylo)),             \
                       pk_mul(qz2, zlo));                                      \
    f32x2 dlo = clamp0(pk_fma(pk_add(dtl, dtl), neg1, pk_add(qw2, wlo)));      \
    f32x2 dth = pk_add(pk_add(pk_mul(qx2, xhi), pk_mul(qy2, yhi)),             \
                       pk_mul(qz2, zhi));                                      \
    f32x2 dhi = clamp0(pk_fma(pk_add(dth, dth), neg1, pk_add(qw2, whi)));      \
    LOADS(P, bb4 + 128)   /* depth-2 prefetch; over-read lands in ws (safe) */ \
    float mn = fminf(fminf(dlo.x, dlo.y), fminf(dhi.x, dhi.y));                \
    if (PRIME && nValid >= 256) {                                              \
      float l = mn;                                                            \
      _Pragma("unroll")                                                        \
      for (int d = 32; d; d >>= 1) l = fmaxf(l, __shfl_xor(l, d));             \
      th = l;   /* >=64 candidates <= th  =>  th >= true 30th (exact) */       \
    }                                                                          \
    u64 anym = __ballot(mn <= th);                                             \
    if (anym) {                                                                \
      bool p0 = dlo.x <= th, p1 = dlo.y <= th, p2 = dhi.x <= th, p3 = dhi.y <= th; \
      u64 m0 = __ballot(p0), m1 = __ballot(p1);                                \
      u64 m2 = __ballot(p2), m3 = __ballot(p3);                                \
      const unsigned j0 = (unsigned)(4 * (bb4 + lane));                        \
      PROC_NB(m0, p0, dlo.x, j0)                                               \
      PROC_NB(m1, p1, dlo.y, j0 + 1)                                           \
      PROC_NB(m2, p2, dhi.x, j0 + 2)                                           \
      PROC_NB(m3, p3, dhi.y, j0 + 3)                                           \
      if (cnt > FLUSH_AT) radix_flush(th, cnt, bd, bj, lane);                  \
    }                                                                          \
  }

  ITERX(A, 0, true)                        // peeled: theta-prime
  if (niter > 1) ITERX(B, 1, false)
  int it = 2;
#pragma unroll 1
  for (; it + 1 < niter; it += 2) {
    ITERX(A, it, false)
    ITERX(B, it + 1, false)
  }
  if (it < niter) ITERX(A, it, false)

  u64 L = finalize_row(th, cnt, bd, bj, gid, lane);
  write_row(rout, true, L, lane, out);
}

extern "C" void kernel_launch(void* const* d_in, const int* in_sizes, int n_in,
                              void* d_out, int out_size, void* d_ws, size_t ws_size,
                              hipStream_t stream) {
  const float* X = (const float*)d_in[0];
  const int* C = (const int*)d_in[1];
  float* gx = (float*)d_ws;
  float* gy = (float*)((char*)d_ws + 32768);
  float* gz = (float*)((char*)d_ws + 65536);
  float* gw = (float*)((char*)d_ws + 98304);
  int* gid = (int*)((char*)d_ws + 131072);
  int* ctr = (int*)((char*)d_ws + 163840);
  __hip_bfloat16* out = (__hip_bfloat16*)d_out;

  zero_kernel<<<1, 64, 0, stream>>>(ctr);
  prep_kernel<<<N / 256, 256, 0, stream>>>(X, C, gx, gy, gz, gw, gid, ctr);
  knn_kernel<<<N / NWAVE, 256, 0, stream>>>(gx, gy, gz, gw, gid, ctr, out);
}